// Round 6
// baseline (932.857 us; speedup 1.0000x reference)
//
#include <hip/hip_runtime.h>
#include <hip/hip_bf16.h>
#include <cstdint>
#include <cstddef>

typedef __attribute__((ext_vector_type(4)))  float f32x4;
typedef __attribute__((ext_vector_type(8)))  short s16x8;
typedef __attribute__((ext_vector_type(8)))  unsigned short u16x8;
typedef __attribute__((ext_vector_type(4)))  unsigned short u16x4;
typedef unsigned short ushort_t;
typedef unsigned long long u64;

#define MFMA_BF16(a, b, c) __builtin_amdgcn_mfma_f32_16x16x32_bf16((a), (b), (c), 0, 0, 0)

constexpr int BATCH  = 4;
constexpr int SEQ    = 2048;
constexpr int NHEAD  = 16;
constexpr int HEADD  = 64;
constexpr int HID    = 1024;
constexpr int BH     = BATCH * NHEAD;   // 64
constexpr int QBLK   = 64;              // q-rows per block (16 per wave)

// scale folded into Q projection: 1/sqrt(64) * log2(e)  (softmax in exp2 domain)
#define QSCALE 0.180336880091961f

// fp32 -> bf16 bits, RNE via compiler
__device__ __forceinline__ ushort_t f2bf(float f) {
  return __builtin_bit_cast(ushort_t, __float2bfloat16(f));
}

// Swizzled Ps offset (ushort elems): row stride 136; chunk XOR keeps both the
// scalar write side and the b128 read side <=2-way bank aliased.
__device__ __forceinline__ int ps_off(int q, int k) {       // Ps[q=0..63][k=0..127]
  return q * 136 + ((((k >> 3) ^ ((q >> 3) & 7)) & 15) << 3) + (k & 7);
}

// ---------------------------------------------------------------------------
// Fused projections (z=0,1,2 -> Q,K,V) + mask bit-pack (z=3).
// Q,K out: bf16 [B][H][S][D].  V out: bf16 [B][H][D][S]  (transposed for attn).
// Unchanged from R3 (verified good).
// ---------------------------------------------------------------------------
__global__ __launch_bounds__(256, 2) void proj_fused_kernel(
    const float* __restrict__ q_in, const float* __restrict__ k_in,
    const float* __restrict__ v_in,
    const float* __restrict__ w_q, const float* __restrict__ b_q,
    const float* __restrict__ w_k, const float* __restrict__ b_k,
    const float* __restrict__ w_v, const float* __restrict__ b_v,
    ushort_t* __restrict__ Qp, ushort_t* __restrict__ Kp,
    ushort_t* __restrict__ Vp,
    const int* __restrict__ mask, u64* __restrict__ pm) {
  const int z = blockIdx.z;
  if (z == 3) {
    const int nwords = BATCH * SEQ * SEQ / 64;  // 262144
    const int lane = threadIdx.x & 63;
    int wid = (blockIdx.y * gridDim.x + blockIdx.x) * 4 + (threadIdx.x >> 6);
    const int step = gridDim.x * gridDim.y * 4;
    for (; wid < nwords; wid += step) {
      int mv = mask[(size_t)wid * 64 + lane];
      u64 bits = __ballot(mv != 0);
      if (lane == 0) pm[wid] = bits;
    }
    return;
  }
  const float* X    = (z == 0) ? q_in : (z == 1) ? k_in : v_in;
  const float* W    = (z == 0) ? w_q : (z == 1) ? w_k : w_v;
  const float* bias = (z == 0) ? b_q : (z == 1) ? b_k : b_v;
  const float scale = (z == 0) ? QSCALE : 1.0f;

  __shared__ ushort_t As[128 * 72];
  __shared__ ushort_t Bs[128 * 72];
  const int tid  = threadIdx.x;
  const int lane = tid & 63;
  const int wave = tid >> 6;
  const int wr = wave >> 1, wc = wave & 1;
  const int lo = lane & 15, hi = lane >> 4;
  const int mb = blockIdx.y, nb = blockIdx.x;

  const int srow = tid >> 4;         // 0..15
  const int scol = (tid & 15) * 4;   // 0..60 (fp32 col)

  f32x4 acc[4][4];
#pragma unroll
  for (int i = 0; i < 4; i++)
#pragma unroll
    for (int j = 0; j < 4; j++) acc[i][j] = (f32x4){0.f, 0.f, 0.f, 0.f};

  const float* xa = X + (size_t)(mb * 128 + srow) * HID + scol;
  const float* xb = W + (size_t)(nb * 128 + srow) * HID + scol;

  for (int k0 = 0; k0 < HID; k0 += 64) {
#pragma unroll
    for (int rr = 0; rr < 128; rr += 16) {
      float4 av = *(const float4*)(xa + (size_t)rr * HID + k0);
      float4 bv = *(const float4*)(xb + (size_t)rr * HID + k0);
      u16x4 a4 = {f2bf(av.x), f2bf(av.y), f2bf(av.z), f2bf(av.w)};
      u16x4 b4 = {f2bf(bv.x), f2bf(bv.y), f2bf(bv.z), f2bf(bv.w)};
      *(u16x4*)(&As[(srow + rr) * 72 + scol]) = a4;
      *(u16x4*)(&Bs[(srow + rr) * 72 + scol]) = b4;
    }
    __syncthreads();
#pragma unroll
    for (int kk = 0; kk < 2; kk++) {
      const int ko = kk * 32 + hi * 8;
      s16x8 af[4], bf[4];
#pragma unroll
      for (int i = 0; i < 4; i++)
        af[i] = *(const s16x8*)(&As[(wr * 64 + i * 16 + lo) * 72 + ko]);
#pragma unroll
      for (int j = 0; j < 4; j++)
        bf[j] = *(const s16x8*)(&Bs[(wc * 64 + j * 16 + lo) * 72 + ko]);
#pragma unroll
      for (int i = 0; i < 4; i++)
#pragma unroll
        for (int j = 0; j < 4; j++)
          acc[i][j] = MFMA_BF16(af[i], bf[j], acc[i][j]);
    }
    __syncthreads();
  }
  if (z != 2) {
    ushort_t* out = (z == 0) ? Qp : Kp;
#pragma unroll
    for (int j = 0; j < 4; j++) {
      const int n = nb * 128 + wc * 64 + j * 16 + lo;
      const float bvn = bias[n];
      const int h = n >> 6, d = n & 63;
#pragma unroll
      for (int i = 0; i < 4; i++) {
        const int m0 = mb * 128 + wr * 64 + i * 16 + hi * 4;
#pragma unroll
        for (int r = 0; r < 4; r++) {
          const int m = m0 + r;
          const int b = m >> 11, s = m & 2047;
          float v = (acc[i][j][r] + bvn) * scale;
          out[(((size_t)(b * NHEAD + h) * SEQ) + s) * HEADD + d] = f2bf(v);
        }
      }
    }
  } else {
#pragma unroll
    for (int j = 0; j < 4; j++) {
      const int n = nb * 128 + wc * 64 + j * 16 + lo;
      const float bvn = bias[n];
      const int h = n >> 6, d = n & 63;
#pragma unroll
      for (int i = 0; i < 4; i++) {
        const int m0 = mb * 128 + wr * 64 + i * 16 + hi * 4;
        const int b = m0 >> 11, s0 = m0 & 2047;
        u16x4 pk = {f2bf(acc[i][j][0] + bvn), f2bf(acc[i][j][1] + bvn),
                    f2bf(acc[i][j][2] + bvn), f2bf(acc[i][j][3] + bvn)};
        *(u16x4*)(Vp + ((size_t)(b * NHEAD + h) * HEADD + d) * SEQ + s0) = pk;
      }
    }
  }
}

// ---------------------------------------------------------------------------
// Fused attention — R3 structure, QBLK=64 (one 16-row strip per wave).
// Sweep1: QK^T (K direct from L1/L2, full 8-j ILP), e=exp2(masked s),
//   lrun+=e, Ps<-bf16(e), PV with unnormalized e. 2 barriers/tile.
// End: l=shfl-reduce(16); ctx=pacc/l; mi=log2(l) stays in registers.
// Sweep2: QK^T recompute, attn=exp2(s-mi). No LDS, no barriers.
// 34816 B LDS + ~120 VGPR -> 3 blocks/CU (vs R3's 2).
// Grid 2048 flat, XCD-chunked: each XCD owns 8 full bh panels (L2-resident).
// ---------------------------------------------------------------------------
__global__ __launch_bounds__(256, 3) void fused_attn_kernel(
    const ushort_t* __restrict__ Qp, const ushort_t* __restrict__ Kp,
    const ushort_t* __restrict__ Vtg, const u64* __restrict__ pm,
    float* __restrict__ attn, float* __restrict__ ctx) {
  extern __shared__ ushort_t smem[];
  ushort_t* Vt = smem;           // [64][136] linear+pad  = 8704 elems
  ushort_t* Ps = smem + 8704;    // [64][136] swizzled    = 8704 elems

  const int tid  = threadIdx.x;
  const int lane = tid & 63, wave = tid >> 6;
  const int lo = lane & 15, hi = lane >> 4;

  const int f  = blockIdx.x;                    // 0..2047
  const int wg = (f & 7) * 256 + (f >> 3);      // XCD-chunked
  const int bh = wg >> 5, qb = wg & 31;
  const int b = bh >> 4, h = bh & 15;

  // ---- Q fragments, direct from global (read once) ----
  const ushort_t* Qg = Qp + ((size_t)bh * SEQ + qb * QBLK + wave * 16) * HEADD;
  s16x8 aq[2];
#pragma unroll
  for (int kk = 0; kk < 2; kk++)
    aq[kk] = *(const s16x8*)(Qg + (size_t)lo * HEADD + kk * 32 + hi * 8);

  const ushort_t* Kg = Kp + (size_t)bh * SEQ * HEADD;          // [s][d]
  const ushort_t* Vg = Vtg + (size_t)bh * HEADD * SEQ;         // [d][s]
  const u64* pmb = pm + (size_t)b * SEQ * 32;
  const int q0 = qb * QBLK + wave * 16;

  float lrun[4] = {0.f, 0.f, 0.f, 0.f};
  f32x4 pacc[4];
#pragma unroll
  for (int jd = 0; jd < 4; jd++) pacc[jd] = (f32x4){0.f, 0.f, 0.f, 0.f};

  const int vr16 = tid >> 4;         // 0..15 (V d-row base)
  const int vc8  = (tid & 15) * 8;   // 0..120 (V s-col)

  // ================= sweep 1: l + PV (unnormalized) =================
  for (int kt = 0; kt < SEQ / 128; kt++) {
    // issue V-tile loads early (latency hides under QK^T)
    u16x8 vreg[4];
#pragma unroll
    for (int it = 0; it < 4; it++)
      vreg[it] = *(const u16x8*)(Vg + (size_t)(it * 16 + vr16) * SEQ + kt * 128 + vc8);

    // QK^T: full 8-j (8 independent accumulators for ILP)
    f32x4 sacc[8];
#pragma unroll
    for (int j = 0; j < 8; j++) sacc[j] = (f32x4){0.f, 0.f, 0.f, 0.f};
#pragma unroll
    for (int j = 0; j < 8; j++) {
      const ushort_t* kr = Kg + (size_t)(kt * 128 + j * 16 + lo) * HEADD + hi * 8;
      s16x8 b0 = *(const s16x8*)(kr);
      s16x8 b1 = *(const s16x8*)(kr + 32);
      sacc[j] = MFMA_BF16(aq[0], b0, sacc[j]);
      sacc[j] = MFMA_BF16(aq[1], b1, sacc[j]);
    }

    // commit V tile to LDS (coalesced u16x8, <=2-way banks)
#pragma unroll
    for (int it = 0; it < 4; it++)
      *(u16x8*)(&Vt[(it * 16 + vr16) * 136 + vc8]) = vreg[it];

    // e = exp2(masked s); lane-local row partial sums; Ps <- bf16(e)
#pragma unroll
    for (int r = 0; r < 4; r++) {
      const int q = q0 + hi * 4 + r;
      const u64* pw = pmb + (size_t)q * 32 + kt * 2;
      u64 s0 = pw[0] >> lo, s1 = pw[1] >> lo;
      const int prow = wave * 16 + hi * 4 + r;
      float tsum = 0.f;
#pragma unroll
      for (int j = 0; j < 8; j++) {
        unsigned bit = (unsigned)((j < 4 ? (s0 >> (j * 16)) : (s1 >> ((j - 4) * 16))) & 1ull);
        float s = bit ? sacc[j][r] : -1e30f;
        float ev = __builtin_amdgcn_exp2f(s);
        tsum += ev;
        Ps[ps_off(prow, j * 16 + lo)] = f2bf(ev);
      }
      lrun[r] += tsum;
    }
    __syncthreads();   // Ps + Vt visible

    // PV: pacc += E @ V  (unnormalized)
#pragma unroll
    for (int kkp = 0; kkp < 4; kkp++) {
      const int ko = kkp * 32 + hi * 8;
      s16x8 ap = *(const s16x8*)(&Ps[ps_off(wave * 16 + lo, ko)]);
#pragma unroll
      for (int jd = 0; jd < 4; jd++) {
        s16x8 bv = *(const s16x8*)(&Vt[(jd * 16 + lo) * 136 + ko]);
        pacc[jd] = MFMA_BF16(ap, bv, pacc[jd]);
      }
    }
    __syncthreads();   // Ps/Vt consumed before next tile's staging
  }

  // ---- finalize: l (single 16-lane reduce), ctx = pacc/l, mi in regs ----
  float il[4], mi[4];
#pragma unroll
  for (int r = 0; r < 4; r++) {
    float l = lrun[r];
#pragma unroll
    for (int off = 1; off < 16; off <<= 1) l += __shfl_xor(l, off);
    il[r] = 1.0f / l;
    mi[r] = __builtin_amdgcn_logf(l);   // log2(l)
  }
#pragma unroll
  for (int jd = 0; jd < 4; jd++)
#pragma unroll
    for (int r = 0; r < 4; r++) {
      const int q = q0 + hi * 4 + r;
      ctx[((size_t)b * SEQ + q) * HID + h * HEADD + jd * 16 + lo] =
          pacc[jd][r] * il[r];
    }

  // ================= sweep 2: attn = exp2(s - mi) =================
  for (int kt = 0; kt < SEQ / 128; kt++) {
    f32x4 sacc[8];
#pragma unroll
    for (int j = 0; j < 8; j++) sacc[j] = (f32x4){0.f, 0.f, 0.f, 0.f};
#pragma unroll
    for (int j = 0; j < 8; j++) {
      const ushort_t* kr = Kg + (size_t)(kt * 128 + j * 16 + lo) * HEADD + hi * 8;
      s16x8 b0 = *(const s16x8*)(kr);
      s16x8 b1 = *(const s16x8*)(kr + 32);
      sacc[j] = MFMA_BF16(aq[0], b0, sacc[j]);
      sacc[j] = MFMA_BF16(aq[1], b1, sacc[j]);
    }
#pragma unroll
    for (int r = 0; r < 4; r++) {
      const int q = q0 + hi * 4 + r;
      const u64* pw = pmb + (size_t)q * 32 + kt * 2;
      u64 s0 = pw[0] >> lo, s1 = pw[1] >> lo;
      const size_t abase = ((size_t)bh * SEQ + q) * SEQ + (size_t)kt * 128;
      const float miv = mi[r];
#pragma unroll
      for (int j = 0; j < 8; j++) {
        unsigned bit = (unsigned)((j < 4 ? (s0 >> (j * 16)) : (s1 >> ((j - 4) * 16))) & 1ull);
        float s = bit ? sacc[j][r] : -1e30f;
        attn[abase + j * 16 + lo] = __builtin_amdgcn_exp2f(s - miv);
      }
    }
  }
}

// ---------------------------------------------------------------------------
extern "C" void kernel_launch(void* const* d_in, const int* in_sizes, int n_in,
                              void* d_out, int out_size, void* d_ws, size_t ws_size,
                              hipStream_t stream) {
  const float* query  = (const float*)d_in[0];
  const float* key_in = (const float*)d_in[1];
  const float* value  = (const float*)d_in[2];
  const int*   mask   = (const int*)d_in[3];
  const float* w_q = (const float*)d_in[4];
  const float* b_q = (const float*)d_in[5];
  const float* w_k = (const float*)d_in[6];
  const float* b_k = (const float*)d_in[7];
  const float* w_v = (const float*)d_in[8];
  const float* b_v = (const float*)d_in[9];

  char* ws = (char*)d_ws;
  const size_t proj_elems = (size_t)BATCH * NHEAD * SEQ * HEADD;  // 8388608
  ushort_t* Qp = (ushort_t*)ws;
  ushort_t* Kp = Qp + proj_elems;
  ushort_t* Vp = Kp + proj_elems;          // [B][H][D][S] transposed
  u64* pmask   = (u64*)(ws + 3 * proj_elems * sizeof(ushort_t));

  float* ctx  = (float*)d_out;                         // [B][S][HID]
  float* attn = ctx + (size_t)BATCH * SEQ * HID;       // [B][H][S][S]

  proj_fused_kernel<<<dim3(HID / 128, (BATCH * SEQ) / 128, 4), dim3(256), 0, stream>>>(
      query, key_in, value, w_q, b_q, w_k, b_k, w_v, b_v, Qp, Kp, Vp, mask, pmask);

  const size_t lds_attn = (8704 + 8704) * sizeof(ushort_t);  // 34816 B
  fused_attn_kernel<<<dim3(BH * (SEQ / QBLK)), dim3(256), lds_attn, stream>>>(
      Qp, Kp, Vp, pmask, attn, ctx);
}

// Round 7
// 723.067 us; speedup vs baseline: 1.2901x; 1.2901x over previous
//
#include <hip/hip_runtime.h>
#include <hip/hip_bf16.h>
#include <cstdint>
#include <cstddef>

typedef __attribute__((ext_vector_type(4)))  float f32x4;
typedef __attribute__((ext_vector_type(8)))  short s16x8;
typedef __attribute__((ext_vector_type(8)))  unsigned short u16x8;
typedef __attribute__((ext_vector_type(4)))  unsigned short u16x4;
typedef unsigned short ushort_t;
typedef unsigned long long u64;

#define MFMA_BF16(a, b, c) __builtin_amdgcn_mfma_f32_16x16x32_bf16((a), (b), (c), 0, 0, 0)

constexpr int BATCH  = 4;
constexpr int SEQ    = 2048;
constexpr int NHEAD  = 16;
constexpr int HEADD  = 64;
constexpr int HID    = 1024;
constexpr int BH     = BATCH * NHEAD;   // 64

// scale folded into Q projection: 1/sqrt(64) * log2(e)  (softmax in exp2 domain)
#define QSCALE 0.180336880091961f

// fp32 -> bf16 bits, RNE via compiler
__device__ __forceinline__ ushort_t f2bf(float f) {
  return __builtin_bit_cast(ushort_t, __float2bfloat16(f));
}

// Swizzled Ps offset (ushort elems): row stride 136; chunk XOR keeps both the
// scalar write side and the b128 read side <=2-way bank aliased.
__device__ __forceinline__ int ps_off(int q, int k) {       // Ps[q=0..127][k=0..127]
  return q * 136 + ((((k >> 3) ^ ((q >> 3) & 7)) & 15) << 3) + (k & 7);
}

// ---------------------------------------------------------------------------
// Fused projections (z=0,1,2 -> Q,K,V) + mask bit-pack (z=3).
// Q,K out: bf16 [B][H][S][D].  V out: bf16 [B][H][D][S]  (transposed for attn).
// Outputs stored non-temporal (consumed later, cross-XCD; don't pollute L2).
// ---------------------------------------------------------------------------
__global__ __launch_bounds__(256, 2) void proj_fused_kernel(
    const float* __restrict__ q_in, const float* __restrict__ k_in,
    const float* __restrict__ v_in,
    const float* __restrict__ w_q, const float* __restrict__ b_q,
    const float* __restrict__ w_k, const float* __restrict__ b_k,
    const float* __restrict__ w_v, const float* __restrict__ b_v,
    ushort_t* __restrict__ Qp, ushort_t* __restrict__ Kp,
    ushort_t* __restrict__ Vp,
    const int* __restrict__ mask, u64* __restrict__ pm) {
  const int z = blockIdx.z;
  if (z == 3) {
    const int nwords = BATCH * SEQ * SEQ / 64;  // 262144
    const int lane = threadIdx.x & 63;
    int wid = (blockIdx.y * gridDim.x + blockIdx.x) * 4 + (threadIdx.x >> 6);
    const int step = gridDim.x * gridDim.y * 4;
    for (; wid < nwords; wid += step) {
      int mv = __builtin_nontemporal_load(mask + (size_t)wid * 64 + lane);
      u64 bits = __ballot(mv != 0);
      if (lane == 0) pm[wid] = bits;
    }
    return;
  }
  const float* X    = (z == 0) ? q_in : (z == 1) ? k_in : v_in;
  const float* W    = (z == 0) ? w_q : (z == 1) ? w_k : w_v;
  const float* bias = (z == 0) ? b_q : (z == 1) ? b_k : b_v;
  const float scale = (z == 0) ? QSCALE : 1.0f;

  __shared__ ushort_t As[128 * 72];
  __shared__ ushort_t Bs[128 * 72];
  const int tid  = threadIdx.x;
  const int lane = tid & 63;
  const int wave = tid >> 6;
  const int wr = wave >> 1, wc = wave & 1;
  const int lo = lane & 15, hi = lane >> 4;
  const int mb = blockIdx.y, nb = blockIdx.x;

  const int srow = tid >> 4;         // 0..15
  const int scol = (tid & 15) * 4;   // 0..60 (fp32 col)

  f32x4 acc[4][4];
#pragma unroll
  for (int i = 0; i < 4; i++)
#pragma unroll
    for (int j = 0; j < 4; j++) acc[i][j] = (f32x4){0.f, 0.f, 0.f, 0.f};

  const float* xa = X + (size_t)(mb * 128 + srow) * HID + scol;
  const float* xb = W + (size_t)(nb * 128 + srow) * HID + scol;

  for (int k0 = 0; k0 < HID; k0 += 64) {
#pragma unroll
    for (int rr = 0; rr < 128; rr += 16) {
      float4 av = *(const float4*)(xa + (size_t)rr * HID + k0);
      float4 bv = *(const float4*)(xb + (size_t)rr * HID + k0);
      u16x4 a4 = {f2bf(av.x), f2bf(av.y), f2bf(av.z), f2bf(av.w)};
      u16x4 b4 = {f2bf(bv.x), f2bf(bv.y), f2bf(bv.z), f2bf(bv.w)};
      *(u16x4*)(&As[(srow + rr) * 72 + scol]) = a4;
      *(u16x4*)(&Bs[(srow + rr) * 72 + scol]) = b4;
    }
    __syncthreads();
#pragma unroll
    for (int kk = 0; kk < 2; kk++) {
      const int ko = kk * 32 + hi * 8;
      s16x8 af[4], bf[4];
#pragma unroll
      for (int i = 0; i < 4; i++)
        af[i] = *(const s16x8*)(&As[(wr * 64 + i * 16 + lo) * 72 + ko]);
#pragma unroll
      for (int j = 0; j < 4; j++)
        bf[j] = *(const s16x8*)(&Bs[(wc * 64 + j * 16 + lo) * 72 + ko]);
#pragma unroll
      for (int i = 0; i < 4; i++)
#pragma unroll
        for (int j = 0; j < 4; j++)
          acc[i][j] = MFMA_BF16(af[i], bf[j], acc[i][j]);
    }
    __syncthreads();
  }
  if (z != 2) {
    ushort_t* out = (z == 0) ? Qp : Kp;
#pragma unroll
    for (int j = 0; j < 4; j++) {
      const int n = nb * 128 + wc * 64 + j * 16 + lo;
      const float bvn = bias[n];
      const int h = n >> 6, d = n & 63;
#pragma unroll
      for (int i = 0; i < 4; i++) {
        const int m0 = mb * 128 + wr * 64 + i * 16 + hi * 4;
#pragma unroll
        for (int r = 0; r < 4; r++) {
          const int m = m0 + r;
          const int b = m >> 11, s = m & 2047;
          float v = (acc[i][j][r] + bvn) * scale;
          __builtin_nontemporal_store(
              f2bf(v), out + (((size_t)(b * NHEAD + h) * SEQ) + s) * HEADD + d);
        }
      }
    }
  } else {
#pragma unroll
    for (int j = 0; j < 4; j++) {
      const int n = nb * 128 + wc * 64 + j * 16 + lo;
      const float bvn = bias[n];
      const int h = n >> 6, d = n & 63;
#pragma unroll
      for (int i = 0; i < 4; i++) {
        const int m0 = mb * 128 + wr * 64 + i * 16 + hi * 4;
        const int b = m0 >> 11, s0 = m0 & 2047;
        u16x4 pk = {f2bf(acc[i][j][0] + bvn), f2bf(acc[i][j][1] + bvn),
                    f2bf(acc[i][j][2] + bvn), f2bf(acc[i][j][3] + bvn)};
        __builtin_nontemporal_store(
            pk, (u16x4*)(Vp + ((size_t)(b * NHEAD + h) * HEADD + d) * SEQ + s0));
      }
    }
  }
}

// ---------------------------------------------------------------------------
// Fused attention — R3 structure (QBLK=128), + nt output stores + h-fast
// within-XCD block order so K/V panels (4MB) + pm slab (~0.3MB) stay
// L2-resident while the 1.07GB attn stream bypasses retention.
// Sweep1: QK^T (K direct from L2), e=exp2(masked s), lrun+=e, Ps<-bf16(e),
//   PV with unnormalized e. End: l=shfl-reduce; ctx=pacc/l (nt); mi=log2(l).
// Sweep2: QK^T recompute, attn=exp2(s-mi) (nt). No LDS, no barriers.
// ---------------------------------------------------------------------------
__global__ __launch_bounds__(256, 2) void fused_attn_kernel(
    const ushort_t* __restrict__ Qp, const ushort_t* __restrict__ Kp,
    const ushort_t* __restrict__ Vtg, const u64* __restrict__ pm,
    float* __restrict__ attn, float* __restrict__ ctx) {
  extern __shared__ ushort_t smem[];
  ushort_t* Vt = smem;           // [64][136] linear+pad  = 8704 elems
  ushort_t* Ps = smem + 8704;    // [128][136] swizzled   = 17408 elems

  const int tid  = threadIdx.x;
  const int lane = tid & 63, wave = tid >> 6;
  const int lo = lane & 15, hi = lane >> 4;

  // XCD f&7 owns bh xcd*8..xcd*8+7. Within an XCD, h varies FASTEST so the
  // ~concurrent blocks share the pm slab (same qb range) across all 8 heads
  // while all 8 K/V panels stay hot.
  const int f   = blockIdx.x;                 // 0..1023
  const int xcd = f & 7, i5 = f >> 3;         // i5: 0..127
  const int bh  = xcd * 8 + (i5 & 7);
  const int qb  = i5 >> 3;                    // 0..15
  const int b = bh >> 4, h = bh & 15;

  // ---- Q fragments, direct from global (read once) ----
  const ushort_t* Qg = Qp + ((size_t)bh * SEQ + qb * 128 + wave * 32) * HEADD;
  s16x8 aq[2][2];
#pragma unroll
  for (int i = 0; i < 2; i++)
#pragma unroll
    for (int kk = 0; kk < 2; kk++)
      aq[i][kk] = *(const s16x8*)(Qg + (size_t)(i * 16 + lo) * HEADD + kk * 32 + hi * 8);

  const ushort_t* Kg = Kp + (size_t)bh * SEQ * HEADD;          // [s][d]
  const ushort_t* Vg = Vtg + (size_t)bh * HEADD * SEQ;         // [d][s]
  const u64* pmb = pm + (size_t)b * SEQ * 32;
  const int q0 = qb * 128 + wave * 32;

  float lrun[2][4];
#pragma unroll
  for (int i = 0; i < 2; i++)
#pragma unroll
    for (int r = 0; r < 4; r++) lrun[i][r] = 0.f;
  f32x4 pacc[2][4];
#pragma unroll
  for (int i = 0; i < 2; i++)
#pragma unroll
    for (int jd = 0; jd < 4; jd++) pacc[i][jd] = (f32x4){0.f, 0.f, 0.f, 0.f};

  const int vr16 = tid >> 4;         // 0..15 (V d-row base)
  const int vc8  = (tid & 15) * 8;   // 0..120 (V s-col)

  // ================= sweep 1: l + PV (unnormalized) =================
  for (int kt = 0; kt < SEQ / 128; kt++) {
    // issue V-tile loads early (latency hides under QK^T)
    u16x8 vreg[4];
#pragma unroll
    for (int it = 0; it < 4; it++)
      vreg[it] = *(const u16x8*)(Vg + (size_t)(it * 16 + vr16) * SEQ + kt * 128 + vc8);

    // QK^T (K fragments direct from global; L2-resident)
    f32x4 sacc[2][8];
#pragma unroll
    for (int i = 0; i < 2; i++)
#pragma unroll
      for (int j = 0; j < 8; j++) sacc[i][j] = (f32x4){0.f, 0.f, 0.f, 0.f};
#pragma unroll
    for (int j = 0; j < 8; j++) {
      const ushort_t* kr = Kg + (size_t)(kt * 128 + j * 16 + lo) * HEADD + hi * 8;
      s16x8 b0 = *(const s16x8*)(kr);
      s16x8 b1 = *(const s16x8*)(kr + 32);
      sacc[0][j] = MFMA_BF16(aq[0][0], b0, sacc[0][j]);
      sacc[1][j] = MFMA_BF16(aq[1][0], b0, sacc[1][j]);
      sacc[0][j] = MFMA_BF16(aq[0][1], b1, sacc[0][j]);
      sacc[1][j] = MFMA_BF16(aq[1][1], b1, sacc[1][j]);
    }

    // commit V tile to LDS (coalesced u16x8, <=2-way banks)
#pragma unroll
    for (int it = 0; it < 4; it++)
      *(u16x8*)(&Vt[(it * 16 + vr16) * 136 + vc8]) = vreg[it];

    // e = exp2(masked s); lane-local row partial sums; Ps <- bf16(e)
#pragma unroll
    for (int i = 0; i < 2; i++)
#pragma unroll
      for (int r = 0; r < 4; r++) {
        const int q = q0 + i * 16 + hi * 4 + r;
        const u64* pw = pmb + (size_t)q * 32 + kt * 2;
        u64 s0 = pw[0] >> lo, s1 = pw[1] >> lo;
        const int prow = wave * 32 + i * 16 + hi * 4 + r;
        float tsum = 0.f;
#pragma unroll
        for (int j = 0; j < 8; j++) {
          unsigned bit = (unsigned)((j < 4 ? (s0 >> (j * 16)) : (s1 >> ((j - 4) * 16))) & 1ull);
          float s = bit ? sacc[i][j][r] : -1e30f;
          float ev = __builtin_amdgcn_exp2f(s);
          tsum += ev;
          Ps[ps_off(prow, j * 16 + lo)] = f2bf(ev);
        }
        lrun[i][r] += tsum;
      }
    __syncthreads();   // Ps + Vt visible

    // PV: pacc += E @ V  (unnormalized)
#pragma unroll
    for (int kkp = 0; kkp < 4; kkp++) {
      const int ko = kkp * 32 + hi * 8;
      s16x8 ap0 = *(const s16x8*)(&Ps[ps_off(wave * 32 + lo, ko)]);
      s16x8 ap1 = *(const s16x8*)(&Ps[ps_off(wave * 32 + 16 + lo, ko)]);
#pragma unroll
      for (int jd = 0; jd < 4; jd++) {
        s16x8 bv = *(const s16x8*)(&Vt[(jd * 16 + lo) * 136 + ko]);
        pacc[0][jd] = MFMA_BF16(ap0, bv, pacc[0][jd]);
        pacc[1][jd] = MFMA_BF16(ap1, bv, pacc[1][jd]);
      }
    }
    __syncthreads();   // Ps/Vt consumed before next tile's staging
  }

  // ---- finalize l (single shuffle-reduce), ctx = pacc / l (nt) ----
  float il[2][4], mi[2][4];
#pragma unroll
  for (int i = 0; i < 2; i++)
#pragma unroll
    for (int r = 0; r < 4; r++) {
      float l = lrun[i][r];
#pragma unroll
      for (int off = 1; off < 16; off <<= 1) l += __shfl_xor(l, off);
      il[i][r] = 1.0f / l;
      mi[i][r] = __builtin_amdgcn_logf(l);   // log2(l)
    }
#pragma unroll
  for (int i = 0; i < 2; i++)
#pragma unroll
    for (int jd = 0; jd < 4; jd++)
#pragma unroll
      for (int r = 0; r < 4; r++) {
        const int q = q0 + i * 16 + hi * 4 + r;
        __builtin_nontemporal_store(
            pacc[i][jd][r] * il[i][r],
            ctx + ((size_t)b * SEQ + q) * HID + h * HEADD + jd * 16 + lo);
      }

  // ================= sweep 2: attn = exp2(s - log2 l), nt stores ==========
  for (int kt = 0; kt < SEQ / 128; kt++) {
    f32x4 sacc[2][8];
#pragma unroll
    for (int i = 0; i < 2; i++)
#pragma unroll
      for (int j = 0; j < 8; j++) sacc[i][j] = (f32x4){0.f, 0.f, 0.f, 0.f};
#pragma unroll
    for (int j = 0; j < 8; j++) {
      const ushort_t* kr = Kg + (size_t)(kt * 128 + j * 16 + lo) * HEADD + hi * 8;
      s16x8 b0 = *(const s16x8*)(kr);
      s16x8 b1 = *(const s16x8*)(kr + 32);
      sacc[0][j] = MFMA_BF16(aq[0][0], b0, sacc[0][j]);
      sacc[1][j] = MFMA_BF16(aq[1][0], b0, sacc[1][j]);
      sacc[0][j] = MFMA_BF16(aq[0][1], b1, sacc[0][j]);
      sacc[1][j] = MFMA_BF16(aq[1][1], b1, sacc[1][j]);
    }
#pragma unroll
    for (int i = 0; i < 2; i++)
#pragma unroll
      for (int r = 0; r < 4; r++) {
        const int q = q0 + i * 16 + hi * 4 + r;
        const u64* pw = pmb + (size_t)q * 32 + kt * 2;
        u64 s0 = pw[0] >> lo, s1 = pw[1] >> lo;
        const size_t abase = ((size_t)bh * SEQ + q) * SEQ + (size_t)kt * 128;
        const float miv = mi[i][r];
#pragma unroll
        for (int j = 0; j < 8; j++) {
          unsigned bit = (unsigned)((j < 4 ? (s0 >> (j * 16)) : (s1 >> ((j - 4) * 16))) & 1ull);
          float s = bit ? sacc[i][j][r] : -1e30f;
          __builtin_nontemporal_store(__builtin_amdgcn_exp2f(s - miv),
                                      attn + abase + j * 16 + lo);
        }
      }
  }
}

// ---------------------------------------------------------------------------
extern "C" void kernel_launch(void* const* d_in, const int* in_sizes, int n_in,
                              void* d_out, int out_size, void* d_ws, size_t ws_size,
                              hipStream_t stream) {
  const float* query  = (const float*)d_in[0];
  const float* key_in = (const float*)d_in[1];
  const float* value  = (const float*)d_in[2];
  const int*   mask   = (const int*)d_in[3];
  const float* w_q = (const float*)d_in[4];
  const float* b_q = (const float*)d_in[5];
  const float* w_k = (const float*)d_in[6];
  const float* b_k = (const float*)d_in[7];
  const float* w_v = (const float*)d_in[8];
  const float* b_v = (const float*)d_in[9];

  char* ws = (char*)d_ws;
  const size_t proj_elems = (size_t)BATCH * NHEAD * SEQ * HEADD;  // 8388608
  ushort_t* Qp = (ushort_t*)ws;
  ushort_t* Kp = Qp + proj_elems;
  ushort_t* Vp = Kp + proj_elems;          // [B][H][D][S] transposed
  u64* pmask   = (u64*)(ws + 3 * proj_elems * sizeof(ushort_t));

  float* ctx  = (float*)d_out;                         // [B][S][HID]
  float* attn = ctx + (size_t)BATCH * SEQ * HID;       // [B][H][S][S]

  proj_fused_kernel<<<dim3(HID / 128, (BATCH * SEQ) / 128, 4), dim3(256), 0, stream>>>(
      query, key_in, value, w_q, b_q, w_k, b_k, w_v, b_v, Qp, Kp, Vp, mask, pmask);

  const size_t lds_attn = (8704 + 17408) * sizeof(ushort_t);  // 52224 B
  fused_attn_kernel<<<dim3(BH * (SEQ / 128)), dim3(256), lds_attn, stream>>>(
      Qp, Kp, Vp, pmask, attn, ctx);
}